// Round 1
// baseline (3035.296 us; speedup 1.0000x reference)
//
#include <hip/hip_runtime.h>
#include <hip/hip_bf16.h>

// Problem: TR2_49555332661799
// diff = G[idx_hi] - G[idx_lo]  (adjacent pairs within stable label groups)
// out  = concat(diff@Wa+ba, diff@Ws+bs, diff@Wc+bc)   [3][M][512] fp32
// N_REL=65536, D_FEAT=3872, D_OUT=512, N_CLASSES=36, M = out_size/1536.
//
// R1 change: GEMM grid linearized + bijective XCD swizzle (m204) so all 12
// n-tiles of an m-tile run consecutively on ONE XCD -> A-tile re-reads hit
// private L2 instead of L3/HBM. GEMM was tile-feed-bound (12x A re-fetch).

#define N_REL 65536
#define K_FEAT 3872
#define D_OUT 512
#define NCLS 36
#define ROW_BYTES_BF16 (K_FEAT * 2)   // 7744
#define NTILES_N 12                   // 1536 / 128

typedef __bf16 bf16x8 __attribute__((ext_vector_type(8)));
typedef __bf16 bf16x4 __attribute__((ext_vector_type(4)));
typedef float  f32x4  __attribute__((ext_vector_type(4)));

// ---------------- index building ----------------

__global__ void zero_hdr_kernel(int* hdr) {
    hdr[threadIdx.x] = 0;   // 256 ints
}

__global__ void hist_kernel(const int* __restrict__ lab, int* __restrict__ hdr) {
    __shared__ int h[64];
    if (threadIdx.x < 64) h[threadIdx.x] = 0;
    __syncthreads();
    int i = blockIdx.x * blockDim.x + threadIdx.x;
    int stride = gridDim.x * blockDim.x;
    for (; i < N_REL; i += stride) atomicAdd(&h[lab[i]], 1);
    __syncthreads();
    if (threadIdx.x < NCLS && h[threadIdx.x]) atomicAdd(&hdr[threadIdx.x], h[threadIdx.x]);
}

// hdr layout (ints): [0..35] counts, [36..72] start (37), [73..108] pair_base
__global__ void prefix_kernel(int* hdr) {
    if (threadIdx.x == 0) {
        int s = 0, nnz = 0;
        for (int g = 0; g < NCLS; g++) {
            int c = hdr[g];
            hdr[36 + g] = s;
            hdr[73 + g] = s - nnz;   // pair_base[g] = start_g - nnz_before(g)
            s += c;
            if (c > 0) nnz++;
        }
        hdr[36 + NCLS] = s;
    }
}

// One block per label: stable scan of all labels, emit consecutive-pair indices.
__global__ void pairs_kernel(const int* __restrict__ lab, const int* __restrict__ hdr,
                             int* __restrict__ idx_lo, int* __restrict__ idx_hi) {
    int g = blockIdx.x;
    int pair_base = hdr[73 + g];
    __shared__ unsigned long long wmask[4];
    __shared__ int carry_prev, carry_rank;
    int tid = threadIdx.x, w = tid >> 6, lane = tid & 63;
    if (tid == 0) { carry_prev = -1; carry_rank = 0; }
    __syncthreads();
    for (int base = 0; base < N_REL; base += 256) {
        int i = base + tid;
        bool m = (lab[i] == g);
        unsigned long long mask = __ballot(m);
        if (lane == 0) wmask[w] = mask;
        __syncthreads();
        if (m) {
            int rank = carry_rank;
            int prev = carry_prev;
            for (int ww = 0; ww < w; ww++) {
                unsigned long long mm = wmask[ww];
                rank += __popcll(mm);
                if (mm) prev = base + (ww << 6) + 63 - __clzll(mm);
            }
            unsigned long long lower = lane ? (mask & ((1ULL << lane) - 1ULL)) : 0ULL;
            rank += __popcll(lower);
            if (lower) prev = base + (w << 6) + 63 - __clzll(lower);
            if (rank > 0) {
                idx_lo[pair_base + rank - 1] = prev;
                idx_hi[pair_base + rank - 1] = i;
            }
        }
        __syncthreads();
        if (tid == 0) {
            int tot = 0, lastp = carry_prev;
            for (int ww = 0; ww < 4; ww++) {
                unsigned long long mm = wmask[ww];
                tot += __popcll(mm);
                if (mm) lastp = base + (ww << 6) + 63 - __clzll(mm);
            }
            carry_rank += tot;
            carry_prev = lastp;
        }
        __syncthreads();
    }
}

// ---------------- weight convert + transpose ----------------
// W_g (3872 x 512 f32, row-major) -> Bt[(g*512+n)][k] bf16 (K-contiguous rows)
__global__ void wconv_kernel(const float* __restrict__ Wa, const float* __restrict__ Ws,
                             const float* __restrict__ Wc, __bf16* __restrict__ Bt) {
    __shared__ float t[32][33];
    int g = blockIdx.z;
    const float* W = (g == 0) ? Wa : ((g == 1) ? Ws : Wc);
    int k0 = blockIdx.x * 32, n0 = blockIdx.y * 32;
    int tx = threadIdx.x, ty = threadIdx.y;   // 32 x 8
    #pragma unroll
    for (int r = 0; r < 4; r++)
        t[ty + 8 * r][tx] = W[(size_t)(k0 + ty + 8 * r) * D_OUT + n0 + tx];
    __syncthreads();
    #pragma unroll
    for (int r = 0; r < 4; r++) {
        int n = ty + 8 * r;
        Bt[(size_t)(g * D_OUT + n0 + n) * K_FEAT + k0 + tx] = (__bf16)t[tx][n];
    }
}

// ---------------- diff + bf16 convert ----------------
// One block per output row (chunk-local). Pad rows (m >= M) zeroed.
__global__ void diff_kernel(const float* __restrict__ G, const int* __restrict__ idx_lo,
                            const int* __restrict__ idx_hi, __bf16* __restrict__ A,
                            int m0, int M) {
    int m = m0 + blockIdx.x;
    __bf16* row = A + (size_t)blockIdx.x * K_FEAT;
    if (m >= M) {
        bf16x4 z = {(__bf16)0.f, (__bf16)0.f, (__bf16)0.f, (__bf16)0.f};
        for (int t = threadIdx.x; t < K_FEAT / 4; t += 256) ((bf16x4*)row)[t] = z;
        return;
    }
    const float4* ph = (const float4*)(G + (size_t)idx_hi[m] * K_FEAT);
    const float4* pl = (const float4*)(G + (size_t)idx_lo[m] * K_FEAT);
    for (int t = threadIdx.x; t < K_FEAT / 4; t += 256) {
        float4 a = ph[t], b = pl[t];
        bf16x4 v = {(__bf16)(a.x - b.x), (__bf16)(a.y - b.y),
                    (__bf16)(a.z - b.z), (__bf16)(a.w - b.w)};
        ((bf16x4*)row)[t] = v;
    }
}

// ---------------- GEMM ----------------
// C[m][n_glob] = sum_k A[m][k] * Bt[n_glob][k]; 128x128 tile, BK=32,
// 4 waves of 64x64 (4x4 of 16x16x32 bf16 MFMA). global_load_lds width 16.
// 1-D grid + bijective XCD swizzle: XCD x gets a contiguous run of seq;
// seq = mtile*12 + ntile, so each m-tile's 12 n-tiles stay on one XCD
// (A-tile becomes L2-resident for its 11 re-reads).

__device__ __forceinline__ void gload_lds16(const void* g, void* l) {
    __builtin_amdgcn_global_load_lds((const __attribute__((address_space(1))) void*)g,
                                     (__attribute__((address_space(3))) void*)l, 16, 0, 0);
}

__global__ __launch_bounds__(256) void gemm_kernel(
    const __bf16* __restrict__ A,    // [mc_pad][3872] chunk
    const __bf16* __restrict__ Bt,   // [1536][3872]
    const float* __restrict__ ba, const float* __restrict__ bs, const float* __restrict__ bc,
    float* __restrict__ out,         // [3][M][512]
    int m0, int M) {
    __shared__ __align__(16) __bf16 As[128 * 32];
    __shared__ __align__(16) __bf16 Bs[128 * 32];
    int tid = threadIdx.x;
    int wid = tid >> 6, lane = tid & 63;

    // bijective XCD swizzle (m204): b -> seq, contiguous seq ranges per XCD
    int b = blockIdx.x;
    int T = gridDim.x;
    int q = T >> 3, r = T & 7;
    int x = b & 7, s = b >> 3;
    int seq = (x < r) ? (x * (q + 1) + s) : (r * (q + 1) + (x - r) * q + s);
    int ntile = seq % NTILES_N;
    int mtile = seq / NTILES_N;

    const char* Ab = (const char*)(A + (size_t)mtile * 128 * K_FEAT);
    const char* Bb = (const char*)(Bt + (size_t)ntile * 128 * K_FEAT);

    // staging: per round, 256 lanes x 16B = 4096 B = 64 rows x 64 B
    int lin0 = wid * 1024 + lane * 16;       // bytes within round
    int rowA0 = lin0 >> 6;                   // 0..63
    int kb0 = lin0 & 63;                     // byte offset within row's 64B k-slab
    const char* gA0 = Ab + (size_t)rowA0 * ROW_BYTES_BF16 + kb0;
    const char* gA1 = Ab + (size_t)(rowA0 + 64) * ROW_BYTES_BF16 + kb0;
    const char* gB0 = Bb + (size_t)rowA0 * ROW_BYTES_BF16 + kb0;
    const char* gB1 = Bb + (size_t)(rowA0 + 64) * ROW_BYTES_BF16 + kb0;
    char* lA0 = (char*)As + wid * 1024;      // wave-uniform LDS base (+ lane*16 by HW)
    char* lA1 = lA0 + 4096;
    char* lB0 = (char*)Bs + wid * 1024;
    char* lB1 = lB0 + 4096;

    int wm = wid & 1, wn = wid >> 1;
    int quad = lane >> 4, r16 = lane & 15;
    const __bf16* aBase = As + (size_t)(wm * 64 + r16) * 32 + quad * 8;
    const __bf16* bBase = Bs + (size_t)(wn * 64 + r16) * 32 + quad * 8;

    f32x4 acc[4][4] = {};

    for (int k0 = 0; k0 < K_FEAT; k0 += 32) {
        gload_lds16(gA0, lA0);
        gload_lds16(gA1, lA1);
        gload_lds16(gB0, lB0);
        gload_lds16(gB1, lB1);
        gA0 += 64; gA1 += 64; gB0 += 64; gB1 += 64;
        __builtin_amdgcn_s_waitcnt(0x0f70);   // vmcnt(0)
        __syncthreads();

        bf16x8 af[4], bfr[4];
        #pragma unroll
        for (int mi = 0; mi < 4; mi++)
            af[mi] = *(const bf16x8*)(aBase + mi * 16 * 32);
        #pragma unroll
        for (int ni = 0; ni < 4; ni++)
            bfr[ni] = *(const bf16x8*)(bBase + ni * 16 * 32);
        #pragma unroll
        for (int mi = 0; mi < 4; mi++)
            #pragma unroll
            for (int ni = 0; ni < 4; ni++)
                acc[mi][ni] = __builtin_amdgcn_mfma_f32_16x16x32_bf16(af[mi], bfr[ni], acc[mi][ni], 0, 0, 0);
        __syncthreads();
    }

    // epilogue: C/D layout col=lane&15 (n), row=quad*4+reg (m)
    #pragma unroll
    for (int ni = 0; ni < 4; ni++) {
        int n_g = ntile * 128 + wn * 64 + ni * 16 + r16;
        int g = n_g >> 9, n = n_g & 511;
        const float* bias = (g == 0) ? ba : ((g == 1) ? bs : bc);
        float bv = bias[n];
        #pragma unroll
        for (int mi = 0; mi < 4; mi++) {
            f32x4 v = acc[mi][ni];
            #pragma unroll
            for (int j = 0; j < 4; j++) {
                int m = mtile * 128 + wm * 64 + mi * 16 + quad * 4 + j;
                int mg = m0 + m;
                if (mg < M) out[((size_t)g * M + mg) * D_OUT + n] = v[j] + bv;
            }
        }
    }
}

// ---------------- launch ----------------

extern "C" void kernel_launch(void* const* d_in, const int* in_sizes, int n_in,
                              void* d_out, int out_size, void* d_ws, size_t ws_size,
                              hipStream_t stream) {
    const float* G  = (const float*)d_in[0];
    const float* Wa = (const float*)d_in[1];
    const float* ba = (const float*)d_in[2];
    const float* Ws = (const float*)d_in[3];
    const float* bs = (const float*)d_in[4];
    const float* Wc = (const float*)d_in[5];
    const float* bc = (const float*)d_in[6];
    const int* lab  = (const int*)d_in[7];
    float* out = (float*)d_out;

    int M = out_size / (3 * D_OUT);

    // ws layout
    char* ws = (char*)d_ws;
    int* hdr = (int*)ws;                                  // 1 KB
    int* idx_lo = (int*)(ws + 1024);                      // 256 KB
    int* idx_hi = (int*)(ws + 1024 + 262144);             // 256 KB
    __bf16* Bt = (__bf16*)(ws + 525312);                  // 1536*3872*2 = 11,894,784 B
    const size_t OFF_A = 525312 + 11894784;               // 12,420,096 (256-aligned)
    __bf16* Ach = (__bf16*)(ws + OFF_A);

    size_t avail = (ws_size > OFF_A) ? (ws_size - OFF_A) : 0;
    int rows_cap = (int)((avail / ROW_BYTES_BF16)) & ~127;
    int Mpad = (M + 127) & ~127;
    int Mc = (rows_cap < Mpad) ? rows_cap : Mpad;
    if (Mc <= 0) return;   // ws too small — cannot run

    zero_hdr_kernel<<<1, 256, 0, stream>>>(hdr);
    hist_kernel<<<64, 256, 0, stream>>>(lab, hdr);
    prefix_kernel<<<1, 64, 0, stream>>>(hdr);
    pairs_kernel<<<NCLS, 256, 0, stream>>>(lab, hdr, idx_lo, idx_hi);
    wconv_kernel<<<dim3(K_FEAT / 32, D_OUT / 32, 3), dim3(32, 8), 0, stream>>>(Wa, Ws, Wc, Bt);

    for (int m0 = 0; m0 < Mpad; m0 += Mc) {
        int mc = Mpad - m0;
        if (mc > Mc) mc = Mc;
        diff_kernel<<<mc, 256, 0, stream>>>(G, idx_lo, idx_hi, Ach, m0, M);
        gemm_kernel<<<dim3(NTILES_N * (mc / 128)), 256, 0, stream>>>(Ach, Bt, ba, bs, bc, out, m0, M);
    }
}